// Round 2
// 537.466 us; speedup vs baseline: 1.1842x; 1.1842x over previous
//
#include <hip/hip_runtime.h>
#include <math.h>

#define N_NODES 50000
#define N_EDGES 800000
#define D 64
#define NB_SCAN ((N_NODES + 255) / 256)   // 196 blocks of 256

typedef float f32x4 __attribute__((ext_vector_type(4)));   // native vector, OK for nontemporal builtins

// ---------------------------------------------------------------------------
// Phase 1: histogram of src -> cnt[n]  (int atomics, 800K ops)
// ---------------------------------------------------------------------------
__global__ __launch_bounds__(256) void hist_kernel(
    const int* __restrict__ edge_index, int* __restrict__ cnt)
{
    int e = blockIdx.x * blockDim.x + threadIdx.x;
    if (e >= N_EDGES) return;
    atomicAdd(&cnt[edge_index[e]], 1);
}

// ---------------------------------------------------------------------------
// Phase 2: exclusive scan of cnt -> offs  (3 tiny kernels)
// ---------------------------------------------------------------------------
__global__ __launch_bounds__(256) void scanA_kernel(
    const int* __restrict__ cnt, int* __restrict__ offs, int* __restrict__ bsum)
{
    __shared__ int tmp[256];
    int tid = threadIdx.x;
    int i = blockIdx.x * 256 + tid;
    int v = (i < N_NODES) ? cnt[i] : 0;
    tmp[tid] = v;
    __syncthreads();
    for (int s = 1; s < 256; s <<= 1) {
        int add = (tid >= s) ? tmp[tid - s] : 0;
        __syncthreads();
        tmp[tid] += add;
        __syncthreads();
    }
    if (i < N_NODES) offs[i] = tmp[tid] - v;          // exclusive
    if (tid == 255) bsum[blockIdx.x] = tmp[255];      // block total
}

__global__ __launch_bounds__(256) void scanB_kernel(int* __restrict__ bsum)
{
    __shared__ int tmp[256];
    int tid = threadIdx.x;
    int v = (tid < NB_SCAN) ? bsum[tid] : 0;
    tmp[tid] = v;
    __syncthreads();
    for (int s = 1; s < 256; s <<= 1) {
        int add = (tid >= s) ? tmp[tid - s] : 0;
        __syncthreads();
        tmp[tid] += add;
        __syncthreads();
    }
    bsum[tid] = tmp[tid] - v;                          // exclusive block offsets
}

__global__ __launch_bounds__(256) void scanC_kernel(
    int* __restrict__ offs, const int* __restrict__ bsum, int* __restrict__ cursor)
{
    int i = blockIdx.x * 256 + threadIdx.x;
    if (i >= N_NODES) return;
    int o = offs[i] + bsum[blockIdx.x];
    offs[i] = o;
    cursor[i] = o;
}

// ---------------------------------------------------------------------------
// Phase 3: bucket edge ids by src (counting-sort fill)
// ---------------------------------------------------------------------------
__global__ __launch_bounds__(256) void fill_kernel(
    const int* __restrict__ edge_index, int* __restrict__ cursor,
    int* __restrict__ bucket)
{
    int e = blockIdx.x * blockDim.x + threadIdx.x;
    if (e >= N_EDGES) return;
    int src = edge_index[e];
    int pos = atomicAdd(&cursor[src], 1);
    bucket[pos] = e;
}

// ---------------------------------------------------------------------------
// Phase 4 (fused): per-node gather-mean + linear + sigmoid.
// One wave per node, lane = feature. Edge rows read coalesced (256 B).
//   * 8-way unrolled gather with 8 independent accumulators -> 8 row loads
//     in flight per wave (was 1). Latency-bound -> bandwidth-bound.
//   * LDS W^T staging padded to stride 65: staging-store bank =
//     (lane+const)%32 (2-way, free) instead of all-64-lanes-same-bank;
//     GEMM read bank = (i+lane)%32 (2-way, free).
// ---------------------------------------------------------------------------
__global__ __launch_bounds__(256) void node_fused_kernel(
    const float* __restrict__ node_attr,
    const float* __restrict__ edge_attr,
    const int* __restrict__ cnt,
    const int* __restrict__ offs,
    const int* __restrict__ bucket,
    const float* __restrict__ W,
    const float* __restrict__ bias,
    float* __restrict__ node_emb)
{
    __shared__ float Wt[D * (D + 1)];     // 16.25 KiB, stride-65 padded
    int tid = threadIdx.x;
    for (int k = tid; k < D * D; k += 256) {
        int o = k >> 6, i = k & 63;
        Wt[i * (D + 1) + o] = W[k];
    }
    __syncthreads();

    int n = blockIdx.x * 4 + (tid >> 6);
    int lane = tid & 63;
    if (n >= N_NODES) return;

    int c   = cnt[n];
    int beg = offs[n];
    const int* __restrict__ bk = bucket + beg;

    float s0 = 0.f, s1 = 0.f, s2 = 0.f, s3 = 0.f;
    float s4 = 0.f, s5 = 0.f, s6 = 0.f, s7 = 0.f;
    int k = 0;
    for (; k + 8 <= c; k += 8) {
        int e0 = bk[k + 0], e1 = bk[k + 1], e2 = bk[k + 2], e3 = bk[k + 3];
        int e4 = bk[k + 4], e5 = bk[k + 5], e6 = bk[k + 6], e7 = bk[k + 7];
        s0 += edge_attr[(size_t)e0 * D + lane];
        s1 += edge_attr[(size_t)e1 * D + lane];
        s2 += edge_attr[(size_t)e2 * D + lane];
        s3 += edge_attr[(size_t)e3 * D + lane];
        s4 += edge_attr[(size_t)e4 * D + lane];
        s5 += edge_attr[(size_t)e5 * D + lane];
        s6 += edge_attr[(size_t)e6 * D + lane];
        s7 += edge_attr[(size_t)e7 * D + lane];
    }
    for (; k + 4 <= c; k += 4) {
        int e0 = bk[k + 0], e1 = bk[k + 1], e2 = bk[k + 2], e3 = bk[k + 3];
        s0 += edge_attr[(size_t)e0 * D + lane];
        s1 += edge_attr[(size_t)e1 * D + lane];
        s2 += edge_attr[(size_t)e2 * D + lane];
        s3 += edge_attr[(size_t)e3 * D + lane];
    }
    for (; k < c; ++k) {
        int e0 = bk[k];
        s0 += edge_attr[(size_t)e0 * D + lane];
    }
    float sum = ((s0 + s1) + (s2 + s3)) + ((s4 + s5) + (s6 + s7));

    float scale = 0.5f / (float)((c > 0) ? c : 1);
    float ms = node_attr[(size_t)n * D + lane] + sum * scale;

    float acc = bias[lane];
    #pragma unroll
    for (int i = 0; i < D; ++i) {
        acc = fmaf(__shfl(ms, i, 64), Wt[i * (D + 1) + lane], acc);
    }
    node_emb[(size_t)n * D + lane] = 1.0f / (1.0f + __expf(-acc));
}

// ---------------------------------------------------------------------------
// Phase 5: out[e] = 0.5*(node_emb[src[e]] + node_emb[dst[e]])
// Output is written once and never re-read -> non-temporal store
// (via native ext_vector_type, HIP float4 is rejected by the builtin).
// ---------------------------------------------------------------------------
__global__ __launch_bounds__(256) void edge_kernel(
    const int* __restrict__ edge_index,
    const f32x4* __restrict__ node_emb,   // [N_NODES*16] vec4
    f32x4* __restrict__ out)              // [N_EDGES*16] vec4
{
    int t = blockIdx.x * blockDim.x + threadIdx.x;   // < E*16 = 12.8M
    if (t >= N_EDGES * 16) return;
    int e = t >> 4;
    int q = t & 15;
    int src = edge_index[e];
    int dst = edge_index[N_EDGES + e];
    f32x4 a = node_emb[src * 16 + q];
    f32x4 c = node_emb[dst * 16 + q];
    f32x4 r = (a + c) * 0.5f;
    __builtin_nontemporal_store(r, out + t);
}

extern "C" void kernel_launch(void* const* d_in, const int* in_sizes, int n_in,
                              void* d_out, int out_size, void* d_ws, size_t ws_size,
                              hipStream_t stream) {
    const float* edge_attr  = (const float*)d_in[0];
    const int*   edge_index = (const int*)d_in[1];
    const float* node_attr  = (const float*)d_in[2];
    const float* W          = (const float*)d_in[3];
    const float* bias       = (const float*)d_in[4];
    float* out = (float*)d_out;

    // Workspace layout:
    //   cnt    : int[N_NODES]      @ 0
    //   offs   : int[N_NODES]      @ 200000 B
    //   bsum   : int[256]          @ 400000 B
    //   cursor : int[N_NODES]      @ 401024 B
    //   bucket : int[N_EDGES]      @ 601024 B
    //   node_emb: float[N_NODES*D] @ 3801024 B (16B-aligned)
    char* ws = (char*)d_ws;
    int*   cnt      = (int*)(ws);
    int*   offs     = (int*)(ws + 200000);
    int*   bsum     = (int*)(ws + 400000);
    int*   cursor   = (int*)(ws + 401024);
    int*   bucket   = (int*)(ws + 601024);
    float* node_emb = (float*)(ws + 3801024);

    hipMemsetAsync(cnt, 0, N_NODES * sizeof(int), stream);

    hist_kernel<<<(N_EDGES + 255) / 256, 256, 0, stream>>>(edge_index, cnt);
    scanA_kernel<<<NB_SCAN, 256, 0, stream>>>(cnt, offs, bsum);
    scanB_kernel<<<1, 256, 0, stream>>>(bsum);
    scanC_kernel<<<NB_SCAN, 256, 0, stream>>>(offs, bsum, cursor);
    fill_kernel<<<(N_EDGES + 255) / 256, 256, 0, stream>>>(edge_index, cursor, bucket);
    node_fused_kernel<<<(N_NODES + 3) / 4, 256, 0, stream>>>(
        node_attr, edge_attr, cnt, offs, bucket, W, bias, node_emb);
    edge_kernel<<<(N_EDGES * 16 + 255) / 256, 256, 0, stream>>>(
        edge_index, (const f32x4*)node_emb, (f32x4*)out);
}